// Round 2
// baseline (2075.681 us; speedup 1.0000x reference)
//
#include <hip/hip_runtime.h>
#include <hip/hip_bf16.h>

// ---------------------------------------------------------------------------
// MF_Transformer: B=128, SL=5000, CH=12, HZ=100 -> tokens M=6400, S=50, D=1024
// L=5, DFF=4096, H=16, dk=64, NC=71. All heavy GEMMs in bf16 MFMA (fp32 acc).
// ---------------------------------------------------------------------------

typedef __attribute__((ext_vector_type(4))) float f32x4;
typedef __attribute__((ext_vector_type(8))) __bf16 bfvec8;

#define MTOT 6400      // B*S
#define DMODEL 1024
#define KEMB 1216      // 1200 padded to multiple of 64

__device__ __forceinline__ unsigned short f2bf(float x) {
    __hip_bfloat16 t = __float2bfloat16(x);
    return *reinterpret_cast<unsigned short*>(&t);
}

__device__ __forceinline__ void gl2lds16(const void* g, void* l) {
    __builtin_amdgcn_global_load_lds(
        (__attribute__((address_space(1))) void*)(g),
        (__attribute__((address_space(3))) void*)(l), 16, 0, 0);
}

// ---------------------------------------------------------------------------
// Transpose-convert: W fp32 (K,N) -> Wt bf16 (N,Kpad), zero-pad k in [K,Kpad)
// ---------------------------------------------------------------------------
__global__ __launch_bounds__(256) void tconv(const float* __restrict__ W,
                                             __hip_bfloat16* __restrict__ Wt,
                                             int K, int N, int Kpad) {
    __shared__ float t[32][33];
    const int n0 = blockIdx.x * 32, k0 = blockIdx.y * 32;
    const int tx = threadIdx.x, ty = threadIdx.y;   // block (32,8)
#pragma unroll
    for (int j = 0; j < 4; ++j) {
        int k = k0 + ty + j * 8, n = n0 + tx;
        float v = (k < K && n < N) ? W[(size_t)k * N + n] : 0.f;
        t[ty + j * 8][tx] = v;
    }
    __syncthreads();
#pragma unroll
    for (int j = 0; j < 4; ++j) {
        int n = n0 + ty + j * 8, k = k0 + tx;
        if (n < N && k < Kpad)
            ((unsigned short*)Wt)[(size_t)n * Kpad + k] = f2bf(t[tx][ty + j * 8]);
    }
}

// ---------------------------------------------------------------------------
// x fp32 (6400,1200) -> bf16 (6400,1216) zero-padded
// ---------------------------------------------------------------------------
__global__ __launch_bounds__(256) void xconv(const float* __restrict__ x,
                                             __hip_bfloat16* __restrict__ xb) {
    int q = blockIdx.x * 256 + threadIdx.x;           // quads: 6400*304
    if (q >= MTOT * (KEMB / 4)) return;
    int m = q / (KEMB / 4), kq = q - m * (KEMB / 4);
    ushort4 o;
    if (kq < 300) {
        float4 v = reinterpret_cast<const float4*>(x + (size_t)m * 1200)[kq];
        o.x = f2bf(v.x); o.y = f2bf(v.y); o.z = f2bf(v.z); o.w = f2bf(v.w);
    } else { o.x = 0; o.y = 0; o.z = 0; o.w = 0; }
    reinterpret_cast<ushort4*>(xb)[q] = o;
}

// ---------------------------------------------------------------------------
// positional encoding table (50,1024) fp32
// ---------------------------------------------------------------------------
__global__ __launch_bounds__(256) void pe_kernel(float* __restrict__ pe) {
    int idx = blockIdx.x * 256 + threadIdx.x;         // 50*512
    if (idx >= 50 * 512) return;
    int s = idx >> 9, i = idx & 511;
    float dv = expf((float)(2 * i) * (-9.210340371976184f / 1024.0f));
    float a = (float)s * dv;
    pe[(s << 10) + 2 * i] = sinf(a);
    pe[(s << 10) + 2 * i + 1] = cosf(a);
}

// ---------------------------------------------------------------------------
// NT bf16 GEMM: C(M,N) = A(M,K) * Bt(N,K)^T   — 128x128 tile, BK=64,
// 256 thr (4 waves 2x2, each 64x64), mfma_f32_16x16x32_bf16,
// global_load_lds w/ pre-swizzled source + XOR-swizzled ds_read (T2).
// FLAGS: 1=bias 2=residual(fp32) 4=relu 8=+pe 16=post scale(g,b) 32=out bf16
// ---------------------------------------------------------------------------
template<int FLAGS>
__global__ void gemm_bt(const __hip_bfloat16* __restrict__ A,
                        const __hip_bfloat16* __restrict__ Bt,
                        float* __restrict__ outF, __hip_bfloat16* __restrict__ outB,
                        const float* __restrict__ bias, const float* __restrict__ res,
                        const float* __restrict__ pe,
                        const float* __restrict__ psg, const float* __restrict__ psb,
                        int M, int N, int K) {
    __shared__ short lds[16384];                       // A: [0,8192) B: [8192,16384) elems
    const int tid = threadIdx.x;
    const int w = tid >> 6, l = tid & 63;
    const int row0 = blockIdx.y * 128, col0 = blockIdx.x * 128;
    const int l15 = l & 15, kof = (l >> 4) << 3;       // frag k-offset (elems)
    const int wr = (w >> 1) << 6, wc = (w & 1) << 6;

    f32x4 acc[4][4];
#pragma unroll
    for (int m = 0; m < 4; ++m)
#pragma unroll
        for (int n = 0; n < 4; ++n) acc[m][n] = (f32x4){0.f, 0.f, 0.f, 0.f};

    // staging geometry: linear LDS slot -> swizzled global column
    int sr[4], sc[4];
#pragma unroll
    for (int c = 0; c < 4; ++c) {
        int e = c * 2048 + w * 512 + l * 8;            // element index in tile
        int r = e >> 6;
        int cb = (e & 63) << 1;                        // byte col (mult of 16)
        sr[c] = r;
        sc[c] = (cb ^ ((r & 7) << 4)) >> 1;            // element col after swizzle
    }
    const int swz = (l15 & 7) << 4;                    // read-side byte XOR

    for (int k0 = 0; k0 < K; k0 += 64) {
#pragma unroll
        for (int c = 0; c < 4; ++c)
            gl2lds16(A + (size_t)(row0 + sr[c]) * K + (k0 + sc[c]),
                     &lds[c * 2048 + w * 512]);
#pragma unroll
        for (int c = 0; c < 4; ++c)
            gl2lds16(Bt + (size_t)(col0 + sr[c]) * K + (k0 + sc[c]),
                     &lds[8192 + c * 2048 + w * 512]);
        __syncthreads();
#pragma unroll
        for (int kk = 0; kk < 64; kk += 32) {
            bfvec8 af[4], bfr[4];
#pragma unroll
            for (int m = 0; m < 4; ++m) {
                int r = wr + m * 16 + l15;
                af[m] = *(const bfvec8*)((const char*)lds + r * 128 + ((((kk + kof) << 1)) ^ swz));
            }
#pragma unroll
            for (int n = 0; n < 4; ++n) {
                int r = wc + n * 16 + l15;
                bfr[n] = *(const bfvec8*)((const char*)lds + 16384 + r * 128 + ((((kk + kof) << 1)) ^ swz));
            }
#pragma unroll
            for (int m = 0; m < 4; ++m)
#pragma unroll
                for (int n = 0; n < 4; ++n)
                    acc[m][n] = __builtin_amdgcn_mfma_f32_16x16x32_bf16(af[m], bfr[n], acc[m][n], 0, 0, 0);
        }
        __syncthreads();
    }

    // epilogue: C/D map col=lane&15, row=(lane>>4)*4+i  [m89-verified]
    const int rb = row0 + wr + ((l >> 4) << 2);
#pragma unroll
    for (int n = 0; n < 4; ++n) {
        const int cidx = col0 + wc + n * 16 + l15;
        float bv = 0.f, pg = 0.f, pb2 = 0.f;
        if constexpr (FLAGS & 1) bv = bias[cidx];
        if constexpr (FLAGS & 16) {
            pg = 0.99999500003749971f * psg[cidx];      // 1/sqrt(1+1e-5) folded in
            pb2 = psb[cidx];
        }
#pragma unroll
        for (int m = 0; m < 4; ++m) {
#pragma unroll
            for (int i = 0; i < 4; ++i) {
                int r = rb + m * 16 + i;
                float v = acc[m][n][i] + bv;
                if constexpr (FLAGS & 8) v += pe[(r % 50) * N + cidx];
                if constexpr (FLAGS & 4) v = fmaxf(v, 0.f);
                if constexpr (FLAGS & 2) v += res[(size_t)r * N + cidx];
                if constexpr (FLAGS & 16) v = v * pg + pb2;
                if constexpr (FLAGS & 32) ((unsigned short*)outB)[(size_t)r * N + cidx] = f2bf(v);
                else outF[(size_t)r * N + cidx] = v;
            }
        }
    }
}

// ---------------------------------------------------------------------------
// LayerNorm (ddof=1, eps added to std): h fp32 (6400,1024) -> bf16 out
// ---------------------------------------------------------------------------
__device__ __forceinline__ float wave_sum(float v) {
#pragma unroll
    for (int off = 32; off; off >>= 1) v += __shfl_down(v, off);
    return v;
}

__global__ __launch_bounds__(256) void ln_kernel(const float* __restrict__ h,
                                                 const float* __restrict__ g,
                                                 const float* __restrict__ b,
                                                 __hip_bfloat16* __restrict__ out) {
    const int row = blockIdx.x, tid = threadIdx.x;
    const float4 v = reinterpret_cast<const float4*>(h + (size_t)row * 1024)[tid];
    float s = v.x + v.y + v.z + v.w;
    float s2 = v.x * v.x + v.y * v.y + v.z * v.z + v.w * v.w;
    __shared__ float red[8];
    float ws1 = wave_sum(s), ws2 = wave_sum(s2);
    if ((tid & 63) == 0) { red[tid >> 6] = ws1; red[4 + (tid >> 6)] = ws2; }
    __syncthreads();
    float sum = red[0] + red[1] + red[2] + red[3];
    float sum2 = red[4] + red[5] + red[6] + red[7];
    float mean = sum * (1.f / 1024.f);
    float var = fmaxf(0.f, (sum2 - sum * mean) * (1.f / 1023.f));
    float inv = 1.f / (sqrtf(var) + 1e-6f);
    float4 gv = reinterpret_cast<const float4*>(g)[tid];
    float4 bv = reinterpret_cast<const float4*>(b)[tid];
    ushort4 o;
    o.x = f2bf(gv.x * (v.x - mean) * inv + bv.x);
    o.y = f2bf(gv.y * (v.y - mean) * inv + bv.y);
    o.z = f2bf(gv.z * (v.z - mean) * inv + bv.z);
    o.w = f2bf(gv.w * (v.w - mean) * inv + bv.w);
    reinterpret_cast<ushort4*>(out)[(size_t)row * 256 + tid] = o;
}

// ---------------------------------------------------------------------------
// Attention: one block per (b,head). qkv bf16 (6400,3072), S=50, dk=64.
// ---------------------------------------------------------------------------
__global__ __launch_bounds__(256) void attn_k(const __hip_bfloat16* __restrict__ qkv,
                                              __hip_bfloat16* __restrict__ o) {
    __shared__ float Q[50][66];
    __shared__ float Kk[50][66];
    __shared__ float V[50][66];
    __shared__ float P[50][52];
    const int bid = blockIdx.x;
    const int b = bid >> 4, hh = bid & 15;
    const int tid = threadIdx.x;
    const size_t base0 = (size_t)(b * 50) * 3072 + hh * 64;
    for (int idx = tid; idx < 3200; idx += 256) {
        int s = idx >> 6, d = idx & 63;
        size_t p = base0 + (size_t)s * 3072 + d;
        Q[s][d] = __bfloat162float(qkv[p]);
        Kk[s][d] = __bfloat162float(qkv[p + 1024]);
        V[s][d] = __bfloat162float(qkv[p + 2048]);
    }
    __syncthreads();
    for (int e = tid; e < 2500; e += 256) {
        int i = e / 50, j = e - i * 50;
        float acc = 0.f;
#pragma unroll
        for (int d = 0; d < 64; ++d) acc += Q[i][d] * Kk[j][d];
        P[i][j] = acc * 0.125f;                        // 1/sqrt(64)
    }
    __syncthreads();
    if (tid < 50) {
        float mx = -1e30f;
        for (int j = 0; j < 50; ++j) mx = fmaxf(mx, P[tid][j]);
        float sum = 0.f;
        for (int j = 0; j < 50; ++j) { float ev = __expf(P[tid][j] - mx); P[tid][j] = ev; sum += ev; }
        float is = 1.f / sum;
        for (int j = 0; j < 50; ++j) P[tid][j] *= is;
    }
    __syncthreads();
    for (int e = tid; e < 3200; e += 256) {
        int i = e >> 6, d = e & 63;
        float acc = 0.f;
#pragma unroll
        for (int j = 0; j < 50; ++j) acc += P[i][j] * V[j][d];
        o[(size_t)(b * 50 + i) * 1024 + hh * 64 + d] = __float2bfloat16(acc);
    }
}

// ---------------------------------------------------------------------------
// Pool: final LN on the 128 last-token rows + cf_bn scale -> bf16 z (128,1024)
// ---------------------------------------------------------------------------
__global__ __launch_bounds__(256) void pool_kernel(const float* __restrict__ h,
                                                   const float* __restrict__ fg,
                                                   const float* __restrict__ fb,
                                                   const float* __restrict__ cg,
                                                   const float* __restrict__ cb,
                                                   __hip_bfloat16* __restrict__ z) {
    const int bb = blockIdx.x, tid = threadIdx.x;
    const size_t row = (size_t)bb * 50 + 49;
    const float4 v = reinterpret_cast<const float4*>(h + row * 1024)[tid];
    float s = v.x + v.y + v.z + v.w;
    float s2 = v.x * v.x + v.y * v.y + v.z * v.z + v.w * v.w;
    __shared__ float red[8];
    float ws1 = wave_sum(s), ws2 = wave_sum(s2);
    if ((tid & 63) == 0) { red[tid >> 6] = ws1; red[4 + (tid >> 6)] = ws2; }
    __syncthreads();
    float sum = red[0] + red[1] + red[2] + red[3];
    float sum2 = red[4] + red[5] + red[6] + red[7];
    float mean = sum * (1.f / 1024.f);
    float var = fmaxf(0.f, (sum2 - sum * mean) * (1.f / 1023.f));
    float inv = 1.f / (sqrtf(var) + 1e-6f);
    const float INV = 0.99999500003749971f;            // 1/sqrt(1+1e-5)
    float4 gv = reinterpret_cast<const float4*>(fg)[tid];
    float4 bv = reinterpret_cast<const float4*>(fb)[tid];
    float4 cgv = reinterpret_cast<const float4*>(cg)[tid];
    float4 cbv = reinterpret_cast<const float4*>(cb)[tid];
    ushort4 o;
    o.x = f2bf((gv.x * (v.x - mean) * inv + bv.x) * INV * cgv.x + cbv.x);
    o.y = f2bf((gv.y * (v.y - mean) * inv + bv.y) * INV * cgv.y + cbv.y);
    o.z = f2bf((gv.z * (v.z - mean) * inv + bv.z) * INV * cgv.z + cbv.z);
    o.w = f2bf((gv.w * (v.w - mean) * inv + bv.w) * INV * cgv.w + cbv.w);
    reinterpret_cast<ushort4*>(z)[(size_t)bb * 256 + tid] = o;
}

// ---------------------------------------------------------------------------
// Final fc: out(128,71) = z3(128,1024) @ fc_w(1024,71) + fc_b
// ---------------------------------------------------------------------------
__global__ __launch_bounds__(128) void fc_kernel(const __hip_bfloat16* __restrict__ z3,
                                                 const float* __restrict__ fw,
                                                 const float* __restrict__ fbias,
                                                 float* __restrict__ out) {
    __shared__ float zr[1024];
    const int b = blockIdx.x, tid = threadIdx.x;
    for (int i = tid; i < 1024; i += 128) zr[i] = __bfloat162float(z3[(size_t)b * 1024 + i]);
    __syncthreads();
    if (tid < 71) {
        float acc = 0.f;
        for (int k = 0; k < 1024; ++k) acc += zr[k] * fw[k * 71 + tid];
        out[b * 71 + tid] = acc + fbias[tid];
    }
}

// ---------------------------------------------------------------------------
extern "C" void kernel_launch(void* const* d_in, const int* in_sizes, int n_in,
                              void* d_out, int out_size, void* d_ws, size_t ws_size,
                              hipStream_t stream) {
    const float* x       = (const float*)d_in[0];
    const float* embed_w = (const float*)d_in[1];
    const float* attn_w  = (const float*)d_in[2];
    const float* attn_b  = (const float*)d_in[3];
    const float* ff_w1   = (const float*)d_in[4];
    const float* ff_b1   = (const float*)d_in[5];
    const float* ff_w2   = (const float*)d_in[6];
    const float* ff_b2   = (const float*)d_in[7];
    const float* ln_g    = (const float*)d_in[8];
    const float* ln_b    = (const float*)d_in[9];
    const float* fin_g   = (const float*)d_in[10];
    const float* fin_b   = (const float*)d_in[11];
    const float* cf_bn_g = (const float*)d_in[12];
    const float* cf_bn_b = (const float*)d_in[13];
    const float* cf_w    = (const float*)d_in[14];
    const float* cf_b    = (const float*)d_in[15];
    const float* fc_bn_g = (const float*)d_in[16];
    const float* fc_bn_b = (const float*)d_in[17];
    const float* fc_w    = (const float*)d_in[18];
    const float* fc_b    = (const float*)d_in[19];

    char* ws = (char*)d_ws;
    size_t off = 0;
    auto alloc = [&](size_t bytes) { void* p = ws + off; off += (bytes + 255) & ~(size_t)255; return p; };

    // weight staging buffer, reused per layer: qkvT(3072x1024) projT(1024x1024)
    // ff1T(4096x1024) ff2T(1024x4096) = 12.58M elems bf16
    __hip_bfloat16* wbuf = (__hip_bfloat16*)alloc((size_t)12582912 * 2);
    float*          h    = (float*)alloc((size_t)MTOT * DMODEL * 4);
    __hip_bfloat16* abuf = (__hip_bfloat16*)alloc((size_t)MTOT * DMODEL * 2);
    __hip_bfloat16* big  = (__hip_bfloat16*)alloc((size_t)MTOT * 4096 * 2);  // xbf | qkv | ffact
    float*          pe   = (float*)alloc((size_t)50 * 1024 * 4);
    __hip_bfloat16* zbuf = (__hip_bfloat16*)alloc((size_t)128 * 1024 * 2);
    __hip_bfloat16* z3   = (__hip_bfloat16*)alloc((size_t)128 * 1024 * 2);

    __hip_bfloat16* qkvT = wbuf;
    __hip_bfloat16* projT = wbuf + (size_t)3072 * 1024;
    __hip_bfloat16* ff1T = wbuf + (size_t)4096 * 1024;
    __hip_bfloat16* ff2T = wbuf + (size_t)8192 * 1024;

    const dim3 tb(32, 8);

    // ---- prologue: x conversion, PE table, embedding GEMM (+PE) ----
    xconv<<<(MTOT * (KEMB / 4) + 255) / 256, 256, 0, stream>>>(x, big);
    pe_kernel<<<100, 256, 0, stream>>>(pe);
    tconv<<<dim3(32, 38), tb, 0, stream>>>(embed_w, wbuf, 1200, 1024, KEMB);
    gemm_bt<8><<<dim3(8, 50), 256, 0, stream>>>(big, wbuf, h, nullptr,
        nullptr, nullptr, pe, nullptr, nullptr, MTOT, DMODEL, KEMB);

    // ---- 5 transformer layers ----
    for (int i = 0; i < 5; ++i) {
        for (int k = 0; k < 3; ++k)
            tconv<<<dim3(32, 32), tb, 0, stream>>>(attn_w + ((size_t)i * 4 + k) * 1048576,
                                                   qkvT + (size_t)k * 1048576, 1024, 1024, 1024);
        tconv<<<dim3(32, 32), tb, 0, stream>>>(attn_w + ((size_t)i * 4 + 3) * 1048576,
                                               projT, 1024, 1024, 1024);
        tconv<<<dim3(128, 32), tb, 0, stream>>>(ff_w1 + (size_t)i * 4194304, ff1T, 1024, 4096, 1024);
        tconv<<<dim3(32, 128), tb, 0, stream>>>(ff_w2 + (size_t)i * 4194304, ff2T, 4096, 1024, 4096);

        // ln1 -> a
        ln_kernel<<<MTOT, 256, 0, stream>>>(h, ln_g + (size_t)i * 2048, ln_b + (size_t)i * 2048, abuf);
        // qkv = a @ Wqkv + b   (bf16 out)
        gemm_bt<33><<<dim3(24, 50), 256, 0, stream>>>(abuf, qkvT, nullptr, big,
            attn_b + (size_t)i * 4096, nullptr, nullptr, nullptr, nullptr, MTOT, 3072, 1024);
        // attention -> o (reuse abuf)
        attn_k<<<2048, 256, 0, stream>>>(big, abuf);
        // h += o @ Wo + bo
        gemm_bt<3><<<dim3(8, 50), 256, 0, stream>>>(abuf, projT, h, nullptr,
            attn_b + (size_t)i * 4096 + 3072, h, nullptr, nullptr, nullptr, MTOT, DMODEL, 1024);
        // ln2 -> a2
        ln_kernel<<<MTOT, 256, 0, stream>>>(h, ln_g + (size_t)i * 2048 + 1024,
                                            ln_b + (size_t)i * 2048 + 1024, abuf);
        // ffact = relu(a2 @ W1 + b1)  (bf16)
        gemm_bt<37><<<dim3(32, 50), 256, 0, stream>>>(abuf, ff1T, nullptr, big,
            ff_b1 + (size_t)i * 4096, nullptr, nullptr, nullptr, nullptr, MTOT, 4096, 1024);
        // h += ffact @ W2 + b2
        gemm_bt<3><<<dim3(8, 50), 256, 0, stream>>>(big, ff2T, h, nullptr,
            ff_b2 + (size_t)i * 1024, h, nullptr, nullptr, nullptr, MTOT, DMODEL, 4096);
    }

    // ---- head ----
    pool_kernel<<<128, 256, 0, stream>>>(h, fin_g, fin_b, cf_bn_g, cf_bn_b, zbuf);
    tconv<<<dim3(32, 32), tb, 0, stream>>>(cf_w, wbuf, 1024, 1024, 1024);
    gemm_bt<53><<<dim3(8, 1), 256, 0, stream>>>(zbuf, wbuf, nullptr, z3,
        cf_b, nullptr, nullptr, fc_bn_g, fc_bn_b, 128, 1024, 1024);
    fc_kernel<<<128, 128, 0, stream>>>(z3, fc_w, fc_b, (float*)d_out);

    (void)in_sizes; (void)n_in; (void)out_size; (void)ws_size;
}